// Round 7
// baseline (210.762 us; speedup 1.0000x reference)
//
#include <hip/hip_runtime.h>
#include <hip/hip_bf16.h>
#include <math.h>

#define BB 8
#define CC 64
#define HH 128
#define WW 128
#define HO 64
#define WO 128
#define OC 64
#define HW (HH * WW)
#define NPM (BB * 9 * HO * WO)

typedef __attribute__((ext_vector_type(8))) short short8;
typedef __attribute__((ext_vector_type(4))) float floatx4;
typedef float float2v __attribute__((ext_vector_type(2)));
typedef float float2a __attribute__((ext_vector_type(2), aligned(4)));  // 8B load, 4B align ok

union BfBits { __hip_bfloat16 h; short s; };

// ---------------------------------------------------------------------------
// Prep A: w_off/w_msk -> w3[c][256] fp32 contiguous (co*9+k).
// ---------------------------------------------------------------------------
__global__ __launch_bounds__(256) void make_w3(
    const float* __restrict__ w_off, const float* __restrict__ w_msk,
    float* __restrict__ w3)
{
    int i = blockIdx.x * 256 + threadIdx.x;   // 15552 = 27*64*9
    if (i >= 27 * CC * 9) return;
    int kk = i % 9;
    int c  = (i / 9) % CC;
    int co = i / (9 * CC);
    float v = (co < 18) ? w_off[(co * CC + c) * 9 + kk]
                        : w_msk[((co - 18) * CC + c) * 9 + kk];
    w3[c * 256 + co * 9 + kk] = v;
}

// ---------------------------------------------------------------------------
// Prep B: w_conv (o,c,k) fp32 -> W2[k][o][c] bf16 (MFMA A-operand layout).
// ---------------------------------------------------------------------------
__global__ __launch_bounds__(256) void make_w2(
    const float* __restrict__ w_conv, __hip_bfloat16* __restrict__ W2)
{
    int i = blockIdx.x * 256 + threadIdx.x;   // 36864 exactly
    int k = i % 9;
    int c = (i / 9) % CC;
    int o = i / (CC * 9);
    W2[((size_t)k * OC + o) * CC + c] = __float2bfloat16(w_conv[i]);
}

// ---------------------------------------------------------------------------
// Kernel 1: offset+mask conv. amdgpu_waves_per_eu(2,4): scheduler pressure
// target 128-256 VGPR so the one-channel-ahead patch loads (xq) stay in
// flight. (R5/R6: launch_bounds(256,3) did NOT move the target — VGPR stuck
// at 52, loads sunk to use, pipeline deleted.)
// ---------------------------------------------------------------------------
__global__ __launch_bounds__(256)
__attribute__((amdgpu_waves_per_eu(2, 4)))
void om_conv(
    const float* __restrict__ x, const float* __restrict__ w3,
    const float* __restrict__ b_off, const float* __restrict__ b_msk,
    float2v* __restrict__ pypx, float* __restrict__ m_out)
{
    __shared__ float red[4][64][29];   // pad 29 -> conflict-free

    int tid = threadIdx.x;
    int lane = tid & 63;
    int chunk = __builtin_amdgcn_readfirstlane(tid >> 6);

    int bx = blockIdx.x;               // 1024 blocks
    int b = bx & 7;                    // XCD-local batch
    int rest = bx >> 3;                // 128 = 64 h * 2 w-halves
    int h = rest >> 1;
    int w = (rest & 1) * 64 + lane;
    int h2 = 2 * h - 1;
    int wm1 = w - 1;

    int idx9[9];
    float msk9[9];
#pragma unroll
    for (int ky = 0; ky < 3; ++ky) {
        int hy = h2 + ky;
        int hyc = min(max(hy, 0), HH - 1);
        float my = ((unsigned)hy < (unsigned)HH) ? 1.0f : 0.0f;
#pragma unroll
        for (int kx = 0; kx < 3; ++kx) {
            int xw = wm1 + kx;
            int xwc = min(max(xw, 0), WW - 1);
            float mx = ((unsigned)xw < (unsigned)WW) ? 1.0f : 0.0f;
            idx9[ky * 3 + kx] = hyc * WW + xwc;
            msk9[ky * 3 + kx] = my * mx;
        }
    }

    float acc[27];
#pragma unroll
    for (int co = 0; co < 27; ++co) acc[co] = 0.0f;

    const float* xb = x + (size_t)b * (CC * HW) + (size_t)chunk * 16 * HW;

    float xp[9], xq[9];
#pragma unroll
    for (int k = 0; k < 9; ++k) xp[k] = xb[idx9[k]] * msk9[k];

    for (int ci = 0; ci < 16; ++ci) {
        if (ci < 15) {
            const float* xc = xb + (ci + 1) * HW;
#pragma unroll
            for (int k = 0; k < 9; ++k) xq[k] = xc[idx9[k]];
        }
        int c = chunk * 16 + ci;
        const float* wc = w3 + c * 256;     // wave-uniform -> s_load
#pragma unroll
        for (int co = 0; co < 27; ++co) {
            float s = acc[co];
#pragma unroll
            for (int k = 0; k < 9; ++k) s = fmaf(wc[co * 9 + k], xp[k], s);
            acc[co] = s;
        }
#pragma unroll
        for (int k = 0; k < 9; ++k) xp[k] = xq[k] * msk9[k];
    }

#pragma unroll
    for (int co = 0; co < 27; ++co) red[chunk][lane][co] = acc[co];
    __syncthreads();

    if (tid < 64) {
        float s[27];
#pragma unroll
        for (int co = 0; co < 27; ++co)
            s[co] = red[0][lane][co] + red[1][lane][co]
                  + red[2][lane][co] + red[3][lane][co];
        int base = ((b * 9) * HO + h) * WO + w;
#pragma unroll
        for (int k = 0; k < 9; ++k) {
            float2v pp;
            pp.x = s[2 * k] + b_off[2 * k] + (float)(k / 3) + (float)h2;
            pp.y = s[2 * k + 1] + b_off[2 * k + 1] + (float)(k % 3) + (float)wm1;
            pypx[base + k * HO * WO] = pp;
            m_out[base + k * HO * WO] =
                1.0f / (1.0f + __expf(-(s[18 + k] + b_msk[k])));
        }
    }
}

// ---------------------------------------------------------------------------
// Kernel 2: deformable sampling + MFMA matvec. amdgpu_waves_per_eu(2,4) so
// the 16 paired-corner gathers (32 VGPRs) + 9-tap coord preload genuinely
// stay in flight across the MFMA phase (software pipeline depth 1).
// ---------------------------------------------------------------------------
__global__ __launch_bounds__(256)
__attribute__((amdgpu_waves_per_eu(2, 4)))
void dconv_mfma(
    const float* __restrict__ x,
    const float2v* __restrict__ pypx, const float* __restrict__ m_in,
    const __hip_bfloat16* __restrict__ W2,
    float* __restrict__ out)
{
    __shared__ __align__(16) __hip_bfloat16 S[2][32][64];  // 8 KB

    int tid = threadIdx.x;
    int lane = tid & 63;
    int wv = tid >> 6;

    int bx = blockIdx.x;               // 2048 blocks
    int b = bx & 7;
    int rest = bx >> 3;                // 256 = 64 h * 4 w-quarters
    int h = rest >> 2;
    int w0 = (rest & 3) * 32;

    int gpos = tid & 31;
    int cg = tid >> 5;                 // 0..7 -> channels cg*8..+8
    const int m16 = lane & 15;
    const int q = lane >> 4;

    floatx4 acc[2];
    acc[0] = (floatx4){0.f, 0.f, 0.f, 0.f};
    acc[1] = (floatx4){0.f, 0.f, 0.f, 0.f};

    const float* xg = x + (size_t)b * (CC * HW) + (size_t)cg * 8 * HW;
    int pidx = ((b * 9) * HO + h) * WO + w0 + gpos;

    // preload all 9 taps' coords+mask (27 VGPRs)
    float2v pp9[9];
    float mk9[9];
#pragma unroll
    for (int k = 0; k < 9; ++k) {
        pp9[k] = pypx[pidx + k * (HO * WO)];
        mk9[k] = m_in[pidx + k * (HO * WO)];
    }

    float2a P[8], Q[8];
    float cxA, cyA, cxB, cyB;

    auto issue = [&](float2v pp, float mk) {
        float py = pp.x, px = pp.y;
        float y0f = floorf(py), x0f = floorf(px);
        float dy = py - y0f, dx = px - x0f;
        int y0 = (int)y0f, x0 = (int)x0f;
        int y1 = y0 + 1, x1 = x0 + 1;
        bool vy0 = (unsigned)y0 < (unsigned)HH;
        bool vy1 = (unsigned)y1 < (unsigned)HH;
        bool vx0 = (unsigned)x0 < (unsigned)WW;
        bool vx1 = (unsigned)x1 < (unsigned)WW;
        float w00 = (1.0f - dy) * (1.0f - dx) * ((vy0 && vx0) ? mk : 0.0f);
        float w01 = (1.0f - dy) * dx          * ((vy0 && vx1) ? mk : 0.0f);
        float w10 = dy * (1.0f - dx)          * ((vy1 && vx0) ? mk : 0.0f);
        float w11 = dy * dx                   * ((vy1 && vx1) ? mk : 0.0f);
        int xbase = min(max(x0, 0), WW - 2);
        bool s0 = x0 > xbase;
        bool s1 = x1 > xbase;
        cxA = (s0 ? 0.f : w00) + (s1 ? 0.f : w01);
        cyA = (s0 ? w00 : 0.f) + (s1 ? w01 : 0.f);
        cxB = (s0 ? 0.f : w10) + (s1 ? 0.f : w11);
        cyB = (s0 ? w10 : 0.f) + (s1 ? w11 : 0.f);
        int yc0 = min(max(y0, 0), HH - 1);
        int yc1 = min(max(y1, 0), HH - 1);
        int r0 = yc0 * WW + xbase, r1 = yc1 * WW + xbase;
#pragma unroll
        for (int j = 0; j < 8; ++j) {
            P[j] = *(const float2a*)(xg + (size_t)j * HW + r0);
            Q[j] = *(const float2a*)(xg + (size_t)j * HW + r1);
        }
    };

    auto combine_store = [&](int buf) {
        short8 sv;
#pragma unroll
        for (int j = 0; j < 8; ++j) {
            float gv = cxA * P[j].x + cyA * P[j].y
                     + cxB * Q[j].x + cyB * Q[j].y;
            BfBits u; u.h = __float2bfloat16(gv);
            sv[j] = u.s;
        }
        *(short8*)&S[buf][gpos][(cg ^ (gpos & 7)) * 8] = sv;
    };

    issue(pp9[0], mk9[0]);
    combine_store(0);

#pragma unroll
    for (int k = 0; k < 9; ++k) {
        __syncthreads();               // S[k&1] ready for all waves
        if (k < 8) issue(pp9[k + 1], mk9[k + 1]);   // in flight during MFMA
        {
            const __hip_bfloat16* wk =
                W2 + ((size_t)(k * OC) + wv * 16 + m16) * CC + q * 8;
            int buf = k & 1;
#pragma unroll
            for (int s = 0; s < 2; ++s) {
                short8 af = *(const short8*)(wk + s * 32);
                int cb = ((q + 4 * s) ^ (m16 & 7)) * 8;
                short8 bf0 = *(const short8*)&S[buf][m16][cb];
                short8 bf1 = *(const short8*)&S[buf][16 + m16][cb];
                acc[0] = __builtin_amdgcn_mfma_f32_16x16x32_bf16(af, bf0, acc[0], 0, 0, 0);
                acc[1] = __builtin_amdgcn_mfma_f32_16x16x32_bf16(af, bf1, acc[1], 0, 0, 0);
            }
        }
        if (k < 8) combine_store((k + 1) & 1);
    }

    // epilogue: C/D col=lane&15 (pos), row=(lane>>4)*4+reg (o)
#pragma unroll
    for (int nt = 0; nt < 2; ++nt) {
#pragma unroll
        for (int r = 0; r < 4; ++r) {
            int o = wv * 16 + q * 4 + r;
            out[(((size_t)b * OC + o) * HO + h) * WO + w0 + nt * 16 + m16]
                = acc[nt][r];
        }
    }
}

// ---------------------------------------------------------------------------
extern "C" void kernel_launch(void* const* d_in, const int* in_sizes, int n_in,
                              void* d_out, int out_size, void* d_ws, size_t ws_size,
                              hipStream_t stream)
{
    const float* x      = (const float*)d_in[0];
    const float* w_off  = (const float*)d_in[1];
    const float* b_off  = (const float*)d_in[2];
    const float* w_msk  = (const float*)d_in[3];
    const float* b_msk  = (const float*)d_in[4];
    const float* w_conv = (const float*)d_in[5];
    float* out = (float*)d_out;

    float2v* pypx = (float2v*)d_ws;                       // NPM float2
    float* m  = (float*)(pypx + NPM);                     // NPM floats
    __hip_bfloat16* W2 = (__hip_bfloat16*)(m + NPM);      // 36864 bf16
    float* w3 = (float*)(W2 + 9 * OC * CC);               // 16384 floats

    make_w3<<<dim3(61), dim3(256), 0, stream>>>(w_off, w_msk, w3);
    make_w2<<<dim3(144), dim3(256), 0, stream>>>(w_conv, W2);
    om_conv<<<dim3(1024), dim3(256), 0, stream>>>(x, w3, b_off, b_msk, pypx, m);
    dconv_mfma<<<dim3(2048), dim3(256), 0, stream>>>(x, pypx, m, W2, out);
}

// Round 9
// 152.407 us; speedup vs baseline: 1.3829x; 1.3829x over previous
//
#include <hip/hip_runtime.h>
#include <hip/hip_bf16.h>
#include <hip/hip_fp16.h>
#include <math.h>

#define BB 8
#define CC 64
#define HH 128
#define WW 128
#define HO 64
#define WO 128
#define OC 64
#define HW (HH * WW)
#define HOWO (HO * WO)
#define NPM (BB * 9 * HOWO)

typedef __attribute__((ext_vector_type(8))) short short8;
typedef __attribute__((ext_vector_type(4))) float floatx4;

union BfBits { __hip_bfloat16 h; unsigned short s; };

__device__ __forceinline__ float bf2f(unsigned short u) {
    return __uint_as_float(((unsigned int)u) << 16);
}
__device__ __forceinline__ unsigned short f2bf(float f) {
    BfBits b; b.h = __float2bfloat16(f); return b.s;
}

// ---------------------------------------------------------------------------
// Kernel 0: transpose x[b][c][y][w] fp32 -> xT[b][y][w][c] bf16 (channel-last)
// so every bilinear corner / im2col column is a coalesced 128B load.
// ---------------------------------------------------------------------------
__global__ __launch_bounds__(256) void transpose_x(
    const float* __restrict__ x, unsigned short* __restrict__ xT)
{
    __shared__ float T[64][65];        // pad 65 -> conflict-free both phases
    int tid = threadIdx.x;
    int bx = blockIdx.x;               // 2048 = 8b * 128y * 2wtiles
    int b = bx & 7;
    int rest = bx >> 3;
    int y = rest >> 1;
    int w0 = (rest & 1) * 64;

    int wl = tid & 63;
    int grp = tid >> 6;                // 0..3
#pragma unroll
    for (int i = 0; i < 16; ++i) {
        int c = grp * 16 + i;
        T[c][wl] = x[(((size_t)b * CC + c) * HH + y) * WW + w0 + wl];
    }
    __syncthreads();
    int c = tid & 63;
#pragma unroll
    for (int i = 0; i < 16; ++i) {
        int wp = grp * 16 + i;
        xT[(((size_t)b * HH + y) * WW + (w0 + wp)) * 64 + c] = f2bf(T[c][wp]);
    }
}

// ---------------------------------------------------------------------------
// Prep: offset+mask weights -> Wom[32 pad rows][576], K-order kk=(ky*3+kx)*64+c
// ---------------------------------------------------------------------------
__global__ __launch_bounds__(256) void make_wom(
    const float* __restrict__ w_off, const float* __restrict__ w_msk,
    unsigned short* __restrict__ Wom)
{
    int i = blockIdx.x * 256 + threadIdx.x;   // 18432 = 32*576
    if (i >= 32 * 576) return;
    int ch = i / 576;
    int kk = i % 576;
    int xs = kk >> 6;
    int c = kk & 63;
    float v = 0.0f;
    if (ch < 18)      v = w_off[(ch * CC + c) * 9 + xs];
    else if (ch < 27) v = w_msk[((ch - 18) * CC + c) * 9 + xs];
    Wom[i] = f2bf(v);
}

// ---------------------------------------------------------------------------
// Prep: w_conv (o,c,k) fp32 -> W2[k][o][c] bf16 (MFMA A-operand layout).
// ---------------------------------------------------------------------------
__global__ __launch_bounds__(256) void make_w2(
    const float* __restrict__ w_conv, unsigned short* __restrict__ W2)
{
    int i = blockIdx.x * 256 + threadIdx.x;   // 36864 exactly
    int k = i % 9;
    int c = (i / 9) % CC;
    int o = i / (CC * 9);
    W2[((size_t)k * OC + o) * CC + c] = f2bf(w_conv[i]);
}

// ---------------------------------------------------------------------------
// Kernel 1: offset+mask conv as MFMA GEMM over xT (gather-free im2col via
// LDS slab), epilogue computes bilinear coeffs (mask+validity folded, fp16
// packed) and packed clamped row bases (r0 | r1<<14) per (pos,tap).
// Block = 32 pos (fixed b,h,w0), 4 waves = 2 Mtiles x 2 Ntiles, K=576.
// ---------------------------------------------------------------------------
__global__ __launch_bounds__(256) void om_gemm(
    const unsigned short* __restrict__ xT, const unsigned short* __restrict__ Wom,
    const float* __restrict__ b_off, const float* __restrict__ b_msk,
    uint2* __restrict__ CFH, unsigned int* __restrict__ CFP)
{
    __shared__ __align__(16) unsigned short Xs[3][34][72];  // c-stride 72 pad
    __shared__ float omr[27][33];

    int tid = threadIdx.x;
    int bx = blockIdx.x;               // 2048 = 8b * 64h * 4wt
    int b = bx & 7;
    int rest = bx >> 3;
    int h = rest >> 2;
    int w0 = (rest & 3) * 32;
    int h2 = 2 * h - 1;

    // ---- stage 3 rows x 34 cols x 64 ch of xT into LDS (coalesced) ----
    for (int u = tid; u < 816; u += 256) {       // 816 = 3*34*8 x 16B units
        int ky = u / 272;
        int rem = u - ky * 272;
        int col = rem >> 3;
        int cb = rem & 7;
        int hy = h2 + ky;
        int wc = w0 - 1 + col;
        short8 v = {0, 0, 0, 0, 0, 0, 0, 0};
        if ((unsigned)hy < (unsigned)HH && (unsigned)wc < (unsigned)WW) {
            v = *(const short8*)(xT + (((size_t)b * HH + hy) * WW + wc) * 64 + cb * 8);
        }
        *(short8*)&Xs[ky][col][cb * 8] = v;
    }
    __syncthreads();

    // ---- MFMA: wave = (Mtile mt, Ntile nt) ----
    int lane = tid & 63;
    int wv = __builtin_amdgcn_readfirstlane(tid >> 6);
    int mt = wv & 1;
    int nt = wv >> 1;
    int m16 = lane & 15;
    int q = lane >> 4;

    floatx4 acc = (floatx4){0.f, 0.f, 0.f, 0.f};
    const unsigned short* wa = Wom + (mt * 16 + m16) * 576 + q * 8;
#pragma unroll
    for (int t = 0; t < 18; ++t) {
        const int xs = t >> 1;
        const int ky = xs / 3, kx = xs % 3;
        short8 af = *(const short8*)(wa + t * 32);
        short8 bf = *(const short8*)&Xs[ky][nt * 16 + m16 + kx][(t & 1) * 32 + q * 8];
        acc = __builtin_amdgcn_mfma_f32_16x16x32_bf16(af, bf, acc, 0, 0, 0);
    }
#pragma unroll
    for (int r = 0; r < 4; ++r) {
        int ch = mt * 16 + q * 4 + r;
        if (ch < 27) omr[ch][nt * 16 + m16] = acc[r];
    }
    __syncthreads();

    // ---- epilogue: coeffs + row bases per (tap, pos); 288 items, 256 thr ----
    for (int u = tid; u < 288; u += 256) {
        int kk = u >> 5;
        int pos = u & 31;
        float offy = omr[2 * kk][pos] + b_off[2 * kk];
        float offx = omr[2 * kk + 1][pos] + b_off[2 * kk + 1];
        float mk = 1.0f / (1.0f + __expf(-(omr[18 + kk][pos] + b_msk[kk])));
        float py = offy + (float)(kk / 3) + (float)h2;
        float px = offx + (float)(kk % 3) + (float)(w0 + pos - 1);

        float y0f = floorf(py), x0f = floorf(px);
        float dy = py - y0f, dx = px - x0f;
        int y0 = (int)y0f, x0 = (int)x0f;
        int y1 = y0 + 1, x1 = x0 + 1;
        bool vy0 = (unsigned)y0 < (unsigned)HH;
        bool vy1 = (unsigned)y1 < (unsigned)HH;
        bool vx0 = (unsigned)x0 < (unsigned)WW;
        bool vx1 = (unsigned)x1 < (unsigned)WW;
        float w00 = (1.0f - dy) * (1.0f - dx) * ((vy0 && vx0) ? mk : 0.0f);
        float w01 = (1.0f - dy) * dx          * ((vy0 && vx1) ? mk : 0.0f);
        float w10 = dy * (1.0f - dx)          * ((vy1 && vx0) ? mk : 0.0f);
        float w11 = dy * dx                   * ((vy1 && vx1) ? mk : 0.0f);
        int xbase = min(max(x0, 0), WW - 2);
        bool s0 = x0 > xbase;
        bool s1 = x1 > xbase;
        float cxA = (s0 ? 0.f : w00) + (s1 ? 0.f : w01);
        float cyA = (s0 ? w00 : 0.f) + (s1 ? w01 : 0.f);
        float cxB = (s0 ? 0.f : w10) + (s1 ? 0.f : w11);
        float cyB = (s0 ? w10 : 0.f) + (s1 ? w11 : 0.f);
        int yc0 = min(max(y0, 0), HH - 1);
        int yc1 = min(max(y1, 0), HH - 1);
        unsigned int r0 = (unsigned)(yc0 * WW + xbase);
        unsigned int r1 = (unsigned)(yc1 * WW + xbase);

        int idx = ((b * 9 + kk) * HO + h) * WO + w0 + pos;
        __half2 hA = __floats2half2_rn(cxA, cyA);
        __half2 hB = __floats2half2_rn(cxB, cyB);
        uint2 hv;
        hv.x = *reinterpret_cast<unsigned int*>(&hA);
        hv.y = *reinterpret_cast<unsigned int*>(&hB);
        CFH[idx] = hv;
        CFP[idx] = r0 | (r1 << 14);
    }
}

// ---------------------------------------------------------------------------
// Kernel 2: deformable sampling + MFMA matvec, channel-last gathers.
// Gather: wave = 64 lanes <-> 64 channels; per (pos,tap): 4 COALESCED 128B
// loads (rows r0,r0+1,r1,r1+1 of xT) + 4 FMAs; coeffs via wave-uniform s_load.
// Each wave owns 8 positions; double-buffered S; one barrier per tap.
// ---------------------------------------------------------------------------
__global__ __launch_bounds__(256) void dconv_mfma(
    const unsigned short* __restrict__ xT,
    const uint2* __restrict__ CFH, const unsigned int* __restrict__ CFP,
    const unsigned short* __restrict__ W2,
    float* __restrict__ out)
{
    __shared__ __align__(16) unsigned short S[2][32][64];  // 8 KB

    int tid = threadIdx.x;
    int lane = tid & 63;
    int wv = __builtin_amdgcn_readfirstlane(tid >> 6);

    int bx = blockIdx.x;               // 2048 = 8b * 64h * 4wt
    int b = bx & 7;
    int rest = bx >> 3;
    int h = rest >> 2;
    int w0 = (rest & 3) * 32;

    int c = lane;                      // gather channel
    int p0 = wv * 8;                   // my 8 positions
    const int m16 = lane & 15;
    const int q = lane >> 4;

    floatx4 acc[2];
    acc[0] = (floatx4){0.f, 0.f, 0.f, 0.f};
    acc[1] = (floatx4){0.f, 0.f, 0.f, 0.f};

    const unsigned short* xTb = xT + (size_t)b * HW * 64;
    int cfb = ((b * 9) * HO + h) * WO + w0 + p0;   // + k*HOWO + i

    unsigned short U[8][4];
    float4 c4[8];

    auto issue = [&](int k) {
#pragma unroll
        for (int i = 0; i < 8; ++i) {
            int idx = cfb + k * HOWO + i;          // wave-uniform -> s_load
            uint2 hv = CFH[idx];
            __half2 hA = *reinterpret_cast<__half2*>(&hv.x);
            __half2 hB = *reinterpret_cast<__half2*>(&hv.y);
            c4[i].x = __low2float(hA);
            c4[i].y = __high2float(hA);
            c4[i].z = __low2float(hB);
            c4[i].w = __high2float(hB);
            unsigned int pk = CFP[idx];
            unsigned int r0 = pk & 0x3FFFu;
            unsigned int r1 = pk >> 14;
            const unsigned short* pA = xTb + (size_t)r0 * 64 + c;
            const unsigned short* pB = xTb + (size_t)r1 * 64 + c;
            U[i][0] = pA[0];
            U[i][1] = pA[64];
            U[i][2] = pB[0];
            U[i][3] = pB[64];
        }
    };
    auto combine_store = [&](int buf) {
#pragma unroll
        for (int i = 0; i < 8; ++i) {
            float v = c4[i].x * bf2f(U[i][0]) + c4[i].y * bf2f(U[i][1])
                    + c4[i].z * bf2f(U[i][2]) + c4[i].w * bf2f(U[i][3]);
            int pos = p0 + i;
            S[buf][pos][((c >> 3) ^ (pos & 7)) * 8 + (c & 7)] = f2bf(v);
        }
    };

    issue(0);
    combine_store(0);

#pragma unroll
    for (int k = 0; k < 9; ++k) {
        __syncthreads();               // S[k&1] ready for all waves
        if (k < 8) issue(k + 1);       // coalesced loads in flight during MFMA
        {
            const unsigned short* wk = W2 + ((size_t)(k * OC) + wv * 16 + m16) * CC + q * 8;
            int buf = k & 1;
#pragma unroll
            for (int s = 0; s < 2; ++s) {
                short8 af = *(const short8*)(wk + s * 32);
                int cb = ((q + 4 * s) ^ (m16 & 7)) * 8;
                short8 bf0 = *(const short8*)&S[buf][m16][cb];
                short8 bf1 = *(const short8*)&S[buf][16 + m16][cb];
                acc[0] = __builtin_amdgcn_mfma_f32_16x16x32_bf16(af, bf0, acc[0], 0, 0, 0);
                acc[1] = __builtin_amdgcn_mfma_f32_16x16x32_bf16(af, bf1, acc[1], 0, 0, 0);
            }
        }
        if (k < 8) combine_store((k + 1) & 1);
    }

    // epilogue: C/D col=lane&15 (pos), row=(lane>>4)*4+reg (o)
#pragma unroll
    for (int nt = 0; nt < 2; ++nt) {
#pragma unroll
        for (int r = 0; r < 4; ++r) {
            int o = wv * 16 + q * 4 + r;
            out[(((size_t)b * OC + o) * HO + h) * WO + w0 + nt * 16 + m16]
                = acc[nt][r];
        }
    }
}

// ---------------------------------------------------------------------------
extern "C" void kernel_launch(void* const* d_in, const int* in_sizes, int n_in,
                              void* d_out, int out_size, void* d_ws, size_t ws_size,
                              hipStream_t stream)
{
    const float* x      = (const float*)d_in[0];
    const float* w_off  = (const float*)d_in[1];
    const float* b_off  = (const float*)d_in[2];
    const float* w_msk  = (const float*)d_in[3];
    const float* b_msk  = (const float*)d_in[4];
    const float* w_conv = (const float*)d_in[5];
    float* out = (float*)d_out;

    // workspace layout (~24 MB)
    uint2* CFH = (uint2*)d_ws;                                 // NPM * 8B
    unsigned int* CFP = (unsigned int*)(CFH + NPM);            // NPM * 4B
    unsigned short* xT = (unsigned short*)(CFP + NPM);         // 8*128*128*64 * 2B
    unsigned short* W2 = xT + (size_t)BB * HW * 64;            // 36864 * 2B
    unsigned short* Wom = W2 + 9 * OC * CC;                    // 18432 * 2B

    transpose_x<<<dim3(2048), dim3(256), 0, stream>>>(x, xT);
    make_wom<<<dim3(72), dim3(256), 0, stream>>>(w_off, w_msk, Wom);
    make_w2<<<dim3(144), dim3(256), 0, stream>>>(w_conv, W2);
    om_gemm<<<dim3(2048), dim3(256), 0, stream>>>(xT, Wom, b_off, b_msk, CFH, CFP);
    dconv_mfma<<<dim3(2048), dim3(256), 0, stream>>>(xT, CFH, CFP, W2, out);
}

// Round 10
// 144.510 us; speedup vs baseline: 1.4585x; 1.0546x over previous
//
#include <hip/hip_runtime.h>
#include <hip/hip_bf16.h>
#include <hip/hip_fp16.h>
#include <math.h>

#define BB 8
#define CC 64
#define HH 128
#define WW 128
#define HO 64
#define WO 128
#define OC 64
#define HW (HH * WW)
#define HOWO (HO * WO)

typedef __attribute__((ext_vector_type(8))) short short8;
typedef __attribute__((ext_vector_type(4))) float floatx4;

union BfBits { __hip_bfloat16 h; unsigned short s; };
__device__ __forceinline__ unsigned short f2bf(float f) {
    BfBits b; b.h = __float2bfloat16(f); return b.s;
}
__device__ __forceinline__ float bflo(unsigned int u) {  // low bf16 of pair
    return __uint_as_float(u << 16);
}
__device__ __forceinline__ float bfhi(unsigned int u) {  // high bf16 of pair
    return __uint_as_float(u & 0xFFFF0000u);
}

// ---------------------------------------------------------------------------
// Kernel A: all prep in one dispatch.
//  blocks 0..1023   : transpose x -> xT[b][y][w][c] bf16  AND
//                     xP[b][y][w][c] = pack(bf16 col w, bf16 col w+1)
//                     (one dword load = both bilinear columns, all 64 ch)
//  blocks 1024..1095: Wom[32][576] bf16 (offset+mask GEMM weights, zero-pad)
//  blocks 1096..1239: W2[k][o][c] bf16 (main conv MFMA A-operand layout)
// ---------------------------------------------------------------------------
__global__ __launch_bounds__(256) void prep(
    const float* __restrict__ x,
    const float* __restrict__ w_off, const float* __restrict__ w_msk,
    const float* __restrict__ w_conv,
    unsigned short* __restrict__ xT, unsigned int* __restrict__ xP,
    unsigned short* __restrict__ Wom, unsigned short* __restrict__ W2)
{
    __shared__ float T[64][130];       // stride 130 -> 2-way max (free)
    int tid = threadIdx.x;
    int bx = blockIdx.x;
    if (bx < 1024) {
        int b = bx & 7, y = bx >> 3;
        int wl = tid & 127, c0 = tid >> 7;
#pragma unroll
        for (int i = 0; i < 32; ++i) {
            int c = 2 * i + c0;
            T[c][wl] = x[(((size_t)b * CC + c) * HH + y) * WW + wl];
        }
        __syncthreads();
        int c = tid & 63, wg = tid >> 6;
#pragma unroll
        for (int i = 0; i < 32; ++i) {
            int wp = wg * 32 + i;
            unsigned int lo = f2bf(T[c][wp]);
            unsigned int hi = (wp < 127) ? f2bf(T[c][wp + 1]) : 0u;
            size_t e = (((size_t)b * HH + y) * WW + wp) * 64 + c;
            xT[e] = (unsigned short)lo;
            xP[e] = lo | (hi << 16);
        }
    } else if (bx < 1096) {
        int i = (bx - 1024) * 256 + tid;     // < 18432 = 32*576
        int ch = i / 576, kk = i % 576;
        int xs = kk >> 6, c = kk & 63;
        float v = 0.0f;
        if (ch < 18)      v = w_off[(ch * CC + c) * 9 + xs];
        else if (ch < 27) v = w_msk[((ch - 18) * CC + c) * 9 + xs];
        Wom[i] = f2bf(v);
    } else {
        int i = (bx - 1096) * 256 + tid;     // < 36864
        int k = i % 9, c = (i / 9) % CC, o = i / (CC * 9);
        W2[((size_t)k * OC + o) * CC + c] = f2bf(w_conv[i]);
    }
}

// ---------------------------------------------------------------------------
// Kernel B: FUSED om-GEMM + coeff epilogue + deformable sampling + main MFMA.
// Block = (b, h, 32-pos w-tile), 256 thr. Phases (LDS overlaid):
//  1. stage xT slab Xs[3][34][72]            (bytes 0..14688)
//  2. om GEMM (18 MFMA) -> omr[27][33]       (bytes 14720..18284)
//  3. epilogue -> meta[9*32] uint4 {h2 coeffs, r0*256, r1*256}
//                                            (bytes 8192..12800, overlays Xs)
//  4. 9-tap sampling (2 paired-column dword loads per pos,tap; meta via
//     broadcast ds_read) + double-buffered S (bytes 0..8192, overlays Xs)
//     + main MFMA, one barrier per tap.
// ---------------------------------------------------------------------------
__global__ __launch_bounds__(256) void fused(
    const unsigned short* __restrict__ xT, const unsigned int* __restrict__ xP,
    const unsigned short* __restrict__ Wom, const unsigned short* __restrict__ W2,
    const float* __restrict__ b_off, const float* __restrict__ b_msk,
    float* __restrict__ out)
{
    __shared__ __align__(16) char lds[18304];
    typedef unsigned short XsRow[34][72];
    XsRow* Xs = (XsRow*)lds;                                        // [3][34][72]
    unsigned short (*S)[32][64] = (unsigned short(*)[32][64])lds;   // [2][32][64]
    uint4* meta = (uint4*)(lds + 8192);                             // [288]
    float (*omr)[33] = (float(*)[33])(lds + 14720);                 // [27][33]

    int tid = threadIdx.x;
    int lane = tid & 63;
    int wv = __builtin_amdgcn_readfirstlane(tid >> 6);
    int bx = blockIdx.x;               // 2048 = 8b * 64h * 4wt
    int b = bx & 7;
    int rest = bx >> 3;
    int h = rest >> 2;
    int w0 = (rest & 3) * 32;
    int h2 = 2 * h - 1;
    int m16 = lane & 15, q = lane >> 4;

    // ---- phase 1: stage slab (coalesced 16B) ----
    for (int u = tid; u < 816; u += 256) {       // 816 = 3*34*8
        int ky = u / 272;
        int rem = u - ky * 272;
        int col = rem >> 3, cb = rem & 7;
        int hy = h2 + ky, wc = w0 - 1 + col;
        short8 v = {0, 0, 0, 0, 0, 0, 0, 0};
        if ((unsigned)hy < (unsigned)HH && (unsigned)wc < (unsigned)WW)
            v = *(const short8*)(xT + (((size_t)b * HH + hy) * WW + wc) * 64 + cb * 8);
        *(short8*)&Xs[ky][col][cb * 8] = v;
    }
    __syncthreads();

    // ---- phase 2: om GEMM (wave = 2 Mtiles x 2 Ntiles, K=576) ----
    {
        int mt = wv & 1, nt = wv >> 1;
        floatx4 a = (floatx4){0.f, 0.f, 0.f, 0.f};
        const unsigned short* wa = Wom + (mt * 16 + m16) * 576 + q * 8;
#pragma unroll
        for (int t = 0; t < 18; ++t) {
            int xs = t >> 1, ky = xs / 3, kx = xs % 3;
            short8 af = *(const short8*)(wa + t * 32);
            short8 bf = *(const short8*)&Xs[ky][nt * 16 + m16 + kx][(t & 1) * 32 + q * 8];
            a = __builtin_amdgcn_mfma_f32_16x16x32_bf16(af, bf, a, 0, 0, 0);
        }
#pragma unroll
        for (int r = 0; r < 4; ++r) {
            int ch = mt * 16 + q * 4 + r;
            if (ch < 27) omr[ch][nt * 16 + m16] = a[r];
        }
    }
    __syncthreads();   // omr ready; Xs reads done (meta/S may overlay)

    // ---- phase 3: coeffs + packed row byte-offsets per (tap,pos) ----
    for (int u = tid; u < 288; u += 256) {
        int kk = u >> 5, pos = u & 31;
        float offy = omr[2 * kk][pos] + b_off[2 * kk];
        float offx = omr[2 * kk + 1][pos] + b_off[2 * kk + 1];
        float mk = 1.0f / (1.0f + __expf(-(omr[18 + kk][pos] + b_msk[kk])));
        float py = offy + (float)(kk / 3) + (float)h2;
        float px = offx + (float)(kk % 3) + (float)(w0 + pos - 1);

        float y0f = floorf(py), x0f = floorf(px);
        float dy = py - y0f, dx = px - x0f;
        int y0 = (int)y0f, x0 = (int)x0f;
        int y1 = y0 + 1, x1 = x0 + 1;
        bool vy0 = (unsigned)y0 < (unsigned)HH;
        bool vy1 = (unsigned)y1 < (unsigned)HH;
        bool vx0 = (unsigned)x0 < (unsigned)WW;
        bool vx1 = (unsigned)x1 < (unsigned)WW;
        float w00 = (1.0f - dy) * (1.0f - dx) * ((vy0 && vx0) ? mk : 0.0f);
        float w01 = (1.0f - dy) * dx          * ((vy0 && vx1) ? mk : 0.0f);
        float w10 = dy * (1.0f - dx)          * ((vy1 && vx0) ? mk : 0.0f);
        float w11 = dy * dx                   * ((vy1 && vx1) ? mk : 0.0f);
        int xbase = min(max(x0, 0), WW - 2);
        bool s0 = x0 > xbase;
        bool s1 = x1 > xbase;
        float cxA = (s0 ? 0.f : w00) + (s1 ? 0.f : w01);
        float cyA = (s0 ? w00 : 0.f) + (s1 ? w01 : 0.f);
        float cxB = (s0 ? 0.f : w10) + (s1 ? 0.f : w11);
        float cyB = (s0 ? w10 : 0.f) + (s1 ? w11 : 0.f);
        int yc0 = min(max(y0, 0), HH - 1);
        int yc1 = min(max(y1, 0), HH - 1);

        __half2 hA = __floats2half2_rn(cxA, cyA);
        __half2 hB = __floats2half2_rn(cxB, cyB);
        uint4 mu;
        mu.x = __builtin_bit_cast(unsigned int, hA);
        mu.y = __builtin_bit_cast(unsigned int, hB);
        mu.z = (unsigned)(yc0 * WW + xbase) * 256u;   // row byte offset in xP
        mu.w = (unsigned)(yc1 * WW + xbase) * 256u;
        meta[u] = mu;
    }
    __syncthreads();

    // ---- phase 4: sampling + main MFMA ----
    int p0 = wv * 8;                   // my 8 positions
    int c = lane;                      // gather channel
    const char* xPb = (const char*)(xP + (size_t)b * HW * 64);
    floatx4 acc0 = (floatx4){0.f, 0.f, 0.f, 0.f};
    floatx4 acc1 = (floatx4){0.f, 0.f, 0.f, 0.f};

    uint4 M[8];
    unsigned int G0[8], G1[8];

    auto issue = [&](int k) {
#pragma unroll
        for (int i = 0; i < 8; ++i) {
            M[i] = meta[k * 32 + p0 + i];          // broadcast ds_read
            G0[i] = *(const unsigned int*)(xPb + M[i].z + 4 * c);
            G1[i] = *(const unsigned int*)(xPb + M[i].w + 4 * c);
        }
    };
    auto store = [&](int buf) {
#pragma unroll
        for (int i = 0; i < 8; ++i) {
            __half2 hA = __builtin_bit_cast(__half2, M[i].x);
            __half2 hB = __builtin_bit_cast(__half2, M[i].y);
            float v = __low2float(hA) * bflo(G0[i]) + __high2float(hA) * bfhi(G0[i])
                    + __low2float(hB) * bflo(G1[i]) + __high2float(hB) * bfhi(G1[i]);
            int pos = p0 + i;
            S[buf][pos][((c >> 3) ^ (pos & 7)) * 8 + (c & 7)] = f2bf(v);
        }
    };

    issue(0);
    store(0);

#pragma unroll
    for (int k = 0; k < 9; ++k) {
        __syncthreads();               // S[k&1] visible to all waves
        if (k < 8) issue(k + 1);       // loads in flight during MFMA
        {
            const unsigned short* wk = W2 + ((size_t)(k * OC) + wv * 16 + m16) * CC + q * 8;
            int buf = k & 1;
#pragma unroll
            for (int s = 0; s < 2; ++s) {
                short8 af = *(const short8*)(wk + s * 32);
                int cb = ((q + 4 * s) ^ (m16 & 7)) * 8;
                short8 bf0 = *(const short8*)&S[buf][m16][cb];
                short8 bf1 = *(const short8*)&S[buf][16 + m16][cb];
                acc0 = __builtin_amdgcn_mfma_f32_16x16x32_bf16(af, bf0, acc0, 0, 0, 0);
                acc1 = __builtin_amdgcn_mfma_f32_16x16x32_bf16(af, bf1, acc1, 0, 0, 0);
            }
        }
        if (k < 8) store((k + 1) & 1);
    }

    // epilogue: C/D col=lane&15 (pos), row=(lane>>4)*4+reg (o)
#pragma unroll
    for (int nt = 0; nt < 2; ++nt) {
        floatx4 av = nt ? acc1 : acc0;
#pragma unroll
        for (int r = 0; r < 4; ++r) {
            int o = wv * 16 + q * 4 + r;
            out[(((size_t)b * OC + o) * HO + h) * WO + w0 + nt * 16 + m16] = av[r];
        }
    }
}

// ---------------------------------------------------------------------------
extern "C" void kernel_launch(void* const* d_in, const int* in_sizes, int n_in,
                              void* d_out, int out_size, void* d_ws, size_t ws_size,
                              hipStream_t stream)
{
    const float* x      = (const float*)d_in[0];
    const float* w_off  = (const float*)d_in[1];
    const float* b_off  = (const float*)d_in[2];
    const float* w_msk  = (const float*)d_in[3];
    const float* b_msk  = (const float*)d_in[4];
    const float* w_conv = (const float*)d_in[5];
    float* out = (float*)d_out;

    // workspace (~50.4 MB): xT bf16, xP paired-uint, Wom, W2
    unsigned short* xT = (unsigned short*)d_ws;                   // 8*HW*64 * 2B
    unsigned int* xP = (unsigned int*)(xT + (size_t)BB * HW * 64);// 8*HW*64 * 4B
    unsigned short* Wom = (unsigned short*)(xP + (size_t)BB * HW * 64); // 32*576
    unsigned short* W2 = Wom + 32 * 576;                          // 36864

    prep<<<dim3(1240), dim3(256), 0, stream>>>(x, w_off, w_msk, w_conv,
                                               xT, xP, Wom, W2);
    fused<<<dim3(2048), dim3(256), 0, stream>>>(xT, xP, Wom, W2,
                                                b_off, b_msk, out);
}